// Round 6
// baseline (107.893 us; speedup 1.0000x reference)
//
#include <hip/hip_runtime.h>

#define PP 16384
#define SQH 0.70710678118654752440f  // sqrt(0.5)

typedef unsigned int u32;
typedef unsigned short u16;
typedef __attribute__((ext_vector_type(8))) short bfrag;    // 8 bf16
typedef __attribute__((ext_vector_type(4))) float ffrag;    // 16x16 C/D
typedef __attribute__((ext_vector_type(16))) float ffrag16; // 32x32 C/D
typedef __attribute__((ext_vector_type(4))) float f4;

union BU { bfrag v; uint4 u; };

// proven bf16 pair pack (round-half-up).
// r1: inline-asm v_cvt_pk_bf16_f32 broke correctness (absmax 40).
// r2: 4-pt/wave "spill" was nid[4][16] scratch (248 B/thread), NOT a-regs.
// r3: gather issue-count reduction (xG dwordx2) NEUTRAL (latency-bound).
// r4: occupancy 2x NEGATIVE (confounded by scratch); counters exposed scratch.
// r5: scratch-free nid NEUTRAL on 2-pt -> pconv ~27us, fixed cost ~76us.
// r6: retry 4-pt pipeline (r2 structure, proven correct) with int4 nid.
__device__ __forceinline__ u32 pk2(float a, float b) {
  u32 ua = __float_as_uint(a), ub = __float_as_uint(b);
  return ((ua + 0x8000u) >> 16) | ((ub + 0x8000u) & 0xffff0000u);
}

// ---- workspace layout (bytes) ----
// [0, XTB_B)        xTb: (P+1, 8, 16) bf16 old layout (su residual reads)
// [XTB_B, +18432)   WB : phase-2 conv-weight B-frags [2][9][64] uint4
// [+18432, +2048)   WR : residual B-frags [2][64] uint4
// [XG_B, +XTB_B)    xG : gather-permuted copy, pos = col*4 + t
#define XTB_B ((size_t)(PP + 1) * 256)
#define WB_B  XTB_B
#define WR_B  (XTB_B + 18432)
#define XG_B  (WR_B + 2048)
#define XG_W  (XG_B / 4)

// Blocks 0..255: LDS-transpose 64 points each; writes BOTH xTb layouts.
// Blocks 256..260: WB/WR frag packing; block 256 also zeroes the pad rows.
__global__ __launch_bounds__(256) void prep_kernel(
    const float* __restrict__ in_pc, const float* __restrict__ weights,
    const float* __restrict__ weight_res, u32* __restrict__ ws) {
  __shared__ u32 T[64 * 72];  // 64 points x 64 dwords, stride 72 (bank rotation)
  const int blk = blockIdx.x, t = threadIdx.x;
  if (blk < 256) {
    const int p0 = blk * 64;
    const int pl = t >> 2, i4 = t & 3;
#pragma unroll
    for (int b = 0; b < 8; ++b) {  // coalesced: consecutive t -> consecutive 16B
      f4 v = *(const f4*)(in_pc + ((size_t)b * PP + p0 + pl) * 16 + i4 * 4);
      T[pl * 72 + b * 8 + i4 * 2]     = pk2(v.x, v.y);
      T[pl * 72 + b * 8 + i4 * 2 + 1] = pk2(v.z, v.w);
    }
    __syncthreads();
#pragma unroll
    for (int k = 0; k < 4; ++k) {  // old layout: coalesced uint4 copies
      int idx = k * 256 + t;
      int pl2 = idx >> 4, c2 = (idx & 15) * 4;
      uint4 v = *(const uint4*)&T[pl2 * 72 + c2];
      *(uint4*)&ws[(size_t)(p0 + pl2) * 64 + c2] = v;
    }
    // gather layout xG: new dword nd_ (col=nd_>>1, t0=2*(nd_&1)) =
    //   old_u16[t0*32+col] | old_u16[(t0+1)*32+col] << 16
#pragma unroll
    for (int k = 0; k < 4; ++k) {
      int idx = k * 256 + t;
      int pl2 = idx >> 4, m = idx & 15;
      u32 T0 = T[pl2 * 72 + m];
      u32 T1 = T[pl2 * 72 + 16 + m];
      u32 T2 = T[pl2 * 72 + 32 + m];
      u32 T3 = T[pl2 * 72 + 48 + m];
      uint4 w;
      w.x = (T0 & 0xffffu) | (T1 << 16);         // col=2m,   t=0|1
      w.y = (T2 & 0xffffu) | (T3 << 16);         // col=2m,   t=2|3
      w.z = (T0 >> 16)     | (T1 & 0xffff0000u); // col=2m+1, t=0|1
      w.w = (T2 >> 16)     | (T3 & 0xffff0000u); // col=2m+1, t=2|3
      *(uint4*)&ws[XG_W + (size_t)(p0 + pl2) * 64 + m * 4] = w;
    }
    return;
  }
  if (blk == 256 && t < 32) {  // zero pad row PP in both layouts
    *(uint2*)&ws[(size_t)PP * 64 + t * 2] = make_uint2(0u, 0u);
    *(uint2*)&ws[XG_W + (size_t)PP * 64 + t * 2] = make_uint2(0u, 0u);
  }
  int e = (blk - 256) * 256 + t;
  if (e < 1152) {  // WB frag (nt, ks, l): B[k=ks*32+(l>>4)*8+j][n=nt*16+(l&15)]
    int nt = e / 576, rem = e - nt * 576;
    int ks = rem >> 6, l = rem & 63;
    int quad = l >> 4, n = l & 15;
    int k0 = ks * 32 + quad * 8;
    uint4 pkd = make_uint4(0u, 0u, 0u, 0u);
    if (k0 < 272) {
      int w = k0 >> 4, i0 = k0 & 15;
      const float* src = weights + w * 512 + (nt * 16 + n) * 16 + i0;
      f4 lo = *(const f4*)src;
      f4 hi = *(const f4*)(src + 4);
      pkd = make_uint4(pk2(lo.x, lo.y), pk2(lo.z, lo.w), pk2(hi.x, hi.y), pk2(hi.z, hi.w));
    }
    *(uint4*)((char*)ws + WB_B + (size_t)e * 16) = pkd;
  } else if (e < 1280) {  // WR frag
    int l2 = e - 1152, nt = l2 >> 6, l = l2 & 63;
    int quad = l >> 4, n = l & 15;
    uint4 pkd = make_uint4(0u, 0u, 0u, 0u);
    if (quad < 2) {
      const float* src = weight_res + (nt * 16 + n) * 16 + quad * 8;
      f4 lo = *(const f4*)src;
      f4 hi = *(const f4*)(src + 4);
      pkd = make_uint4(pk2(lo.x, lo.y), pk2(lo.z, lo.w), pk2(hi.x, hi.y), pk2(hi.z, hi.w));
    }
    *(uint4*)((char*)ws + WR_B + (size_t)(e - 1152) * 16) = pkd;
  }
}

// gather one point's 16 neighbor rows into packed A dwords.
// Neighbor ids arrive as two int4 (this half-wave's 8 rows) — component
// access only, so everything stays in VGPRs (no rule-#20 scratch array).
__device__ __forceinline__ void gather_pt(u32 (&ad)[4][4], int4 na, int4 nb,
                                          const u16* __restrict__ xG, int col) {
#define GJ(j, r0, r1)                                                        \
  {                                                                          \
    uint2 d = *(const uint2*)(xG + (size_t)(u32)(r0) * 128 + col * 4);       \
    uint2 e = *(const uint2*)(xG + (size_t)(u32)(r1) * 128 + col * 4);       \
    ad[0][j] = (d.x & 0xffffu) | (e.x << 16);                                \
    ad[1][j] = (d.x >> 16)     | (e.x & 0xffff0000u);                        \
    ad[2][j] = (d.y & 0xffffu) | (e.y << 16);                                \
    ad[3][j] = (d.y >> 16)     | (e.y & 0xffff0000u);                        \
  }
  GJ(0, na.x, na.y)
  GJ(1, na.z, na.w)
  GJ(2, nb.x, nb.y)
  GJ(3, nb.z, nb.w)
#undef GJ
}

// Main: 1024 blocks x 4 waves; FOUR points per wave as a 2-pair pipelined
// loop (structure harness-proven correct in r2; its scratch defect fixed by
// int4 nid). a0/a1 (32 VGPRs) reused across pairs; pair-1 gathers issue
// under pair-0's phase-2/epilogue. bounds(256,3): <=170 VGPR, no spill —
// LDS caps residency at 4 blocks/CU regardless. Zero barriers.
__global__ __launch_bounds__(256, 3) void pconv_main(
    const u32* __restrict__ ws,
    const float* __restrict__ bias,      // (P, 32) f32
    const float* __restrict__ wwg,       // (P, 16, 17) f32
    const int*  __restrict__ nidg,       // (P, 16) i32
    float* __restrict__ out)             // (8, P, 32) f32
{
  __shared__ __attribute__((aligned(16))) u16 Abuf[4 * 16 * 296];  // 37888 B

  const u16*  __restrict__ xTb = (const u16*)ws;
  const u16*  __restrict__ xG  = (const u16*)((const char*)ws + XG_B);
  const uint4* __restrict__ WB = (const uint4*)((const char*)ws + WB_B);
  const uint4* __restrict__ WR = (const uint4*)((const char*)ws + WR_B);

  const int tid = threadIdx.x;
  const int wid = __builtin_amdgcn_readfirstlane(tid >> 6);
  const int lane = tid & 63;
  const int lo16 = lane & 15, quad = lane >> 4;   // 16x16 MFMA role
  const int col = lane & 31, h = lane >> 5;       // 32x32 MFMA role
  u16* __restrict__ Aw = Abuf + wid * (16 * 296);

  const int pbase = (blockIdx.x * 4 + wid) * 4;   // 4 points per wave

  // zero K-tail [272,288) of all 16 A2 rows (re-done after pair-0 epilogue)
  {
    int r = lane >> 2, c = lane & 3;
    *(uint2*)(Aw + r * 296 + 272 + c * 4) = make_uint2(0u, 0u);
  }

  // ---- prologue: issue ALL independent loads for all 4 points ----
  // neighbor ids: this half-wave's 8 per point, as int4 pairs (VGPRs only)
  const int* nr = nidg + (size_t)pbase * 16 + h * 8;
  int4 n0a = *(const int4*)(nr);
  int4 n0b = *(const int4*)(nr + 4);
  int4 n1a = *(const int4*)(nr + 16);
  int4 n1b = *(const int4*)(nr + 20);
  int4 n2a = *(const int4*)(nr + 32);
  int4 n2b = *(const int4*)(nr + 36);
  int4 n3a = *(const int4*)(nr + 48);
  int4 n3b = *(const int4*)(nr + 52);

  BU bb[4];  // phase-1 ww B-frags, packed in-kernel
#pragma unroll
  for (int p = 0; p < 4; ++p) {
    float v[8];
#pragma unroll
    for (int idx = 0; idx < 8; ++idx) {
      float x = 0.f;
      if (col < 17)
        x = wwg[(size_t)(pbase + p) * 272 + (h * 8 + idx) * 17 + col];
      v[idx] = x;
    }
    bb[p].u = make_uint4(pk2(v[0], v[1]), pk2(v[2], v[3]),
                         pk2(v[4], v[5]), pk2(v[6], v[7]));
  }

  // residual B-frags (wave-constant) + residual self rows for both pairs
  BU rb0, rb1;
  rb0.u = WR[lane];
  rb1.u = WR[64 + lane];
  BU su[2];
#pragma unroll
  for (int pp = 0; pp < 2; ++pp) {
    su[pp].u = make_uint4(0u, 0u, 0u, 0u);
    const int p_r = pbase + 2 * pp + (lo16 >> 3), b_r = lo16 & 7;
    if (quad < 2)
      su[pp].u = *(const uint4*)(xTb + (size_t)p_r * 128 + b_r * 16 + quad * 8);
  }

  u32 a0[4][4], a1[4][4];
  gather_pt(a0, n0a, n0b, xG, col);
  gather_pt(a1, n1a, n1b, xG, col);

  // ---- pair loop: 2 points per iteration ----
#pragma unroll
  for (int pp = 0; pp < 2; ++pp) {
    const int p0 = pbase + 2 * pp;

    // phase 1: two points -> A2 in LDS
#pragma unroll
    for (int pt = 0; pt < 2; ++pt) {
      const u32 (&ad)[4][4] = pt ? a1 : a0;
      BU bbv = bb[2 * pp + pt];
#pragma unroll
      for (int t = 0; t < 4; ++t) {
        BU aa;
        aa.u = make_uint4(ad[t][0], ad[t][1], ad[t][2], ad[t][3]);
        ffrag16 c = {};
        c = __builtin_amdgcn_mfma_f32_32x32x16_bf16(aa.v, bbv.v, c, 0, 0, 0);
        if (col < 17) {
#pragma unroll
          for (int q = 0; q < 4; ++q) {
            int r = pt * 8 + 2 * t + (q >> 1);
            int i0 = 4 * h + 8 * (q & 1);
            u16* dst = Aw + r * 296 + col * 16 + i0;
            *(uint2*)dst = make_uint2(pk2(c[4 * q + 0], c[4 * q + 1]),
                                      pk2(c[4 * q + 2], c[4 * q + 3]));
          }
        }
      }
    }

    // prefetch next pair's gathers NOW (reuses a0/a1 regs; latency hides
    // under this pair's phase-2 + epilogue)
    if (pp == 0) {
      gather_pt(a0, n2a, n2b, xG, col);
      gather_pt(a1, n3a, n3b, xG, col);
    }

    // bias for this pair (load->use distance covered by phase 2)
    float blo[4], bhi[4];
#pragma unroll
    for (int j = 0; j < 4; ++j) {
      int p_e = p0 + ((quad * 4 + j) >> 3);
      blo[j] = bias[(size_t)p_e * 32 + lo16];
      bhi[j] = bias[(size_t)p_e * 32 + 16 + lo16];
    }

    // phase 2: C[16x32] = A2[16x288] * W
    ffrag acc0 = {0.f, 0.f, 0.f, 0.f}, acc1 = {0.f, 0.f, 0.f, 0.f};
#pragma unroll
    for (int ks = 0; ks < 9; ++ks) {
      bfrag af = *(const bfrag*)(Aw + lo16 * 296 + ks * 32 + quad * 8);
      BU b0, b1;
      b0.u = WB[ks * 64 + lane];
      b1.u = WB[576 + ks * 64 + lane];
      acc0 = __builtin_amdgcn_mfma_f32_16x16x32_bf16(af, b0.v, acc0, 0, 0, 0);
      acc1 = __builtin_amdgcn_mfma_f32_16x16x32_bf16(af, b1.v, acc1, 0, 0, 0);
    }
    ffrag rz = {0.f, 0.f, 0.f, 0.f};
    ffrag res0 = __builtin_amdgcn_mfma_f32_16x16x32_bf16(su[pp].v, rb0.v, rz, 0, 0, 0);
    ffrag res1 = __builtin_amdgcn_mfma_f32_16x16x32_bf16(su[pp].v, rb1.v, rz, 0, 0, 0);

    // epilogue: bias/ELU/mix -> LDS f32 [16][40] -> full-line stores
    float* Ef = (float*)Aw;
#pragma unroll
    for (int j = 0; j < 4; ++j) {
      int r = quad * 4 + j;
      float c0 = acc0[j] + blo[j];
      float c1 = acc1[j] + bhi[j];
      float e0 = c0 > 0.f ? c0 : (__expf(c0) - 1.f);
      float e1 = c1 > 0.f ? c1 : (__expf(c1) - 1.f);
      Ef[r * 40 + lo16]      = SQH * e0 + SQH * res0[j];
      Ef[r * 40 + 16 + lo16] = SQH * e1 + SQH * res1[j];
    }
#pragma unroll
    for (int k = 0; k < 2; ++k) {
      int rr = (lane >> 3) + 8 * k;
      int cc = lane & 7;
      f4 v = *(const f4*)(Ef + rr * 40 + cc * 4);
      int p_s = p0 + (rr >> 3), b_s = rr & 7;
      *(f4*)(out + ((size_t)b_s * PP + p_s) * 32 + cc * 4) = v;
    }

    // Ef clobbered A2 rows 0..4 incl. their zero K-tails; re-zero before
    // pair 1's phase 1. Same-wave DS ops are in-order, so this lands after
    // the Ef reads above.
    if (pp == 0) {
      int r = lane >> 2, c = lane & 3;
      *(uint2*)(Aw + r * 296 + 272 + c * 4) = make_uint2(0u, 0u);
    }
  }
}

extern "C" void kernel_launch(void* const* d_in, const int* in_sizes, int n_in,
                              void* d_out, int out_size, void* d_ws, size_t ws_size,
                              hipStream_t stream) {
  const float* in_pc       = (const float*)d_in[0];
  const float* weights     = (const float*)d_in[1];
  const float* bias        = (const float*)d_in[2];
  const float* w_weights   = (const float*)d_in[3];
  const float* weight_res  = (const float*)d_in[4];
  const int*   neighbor_id = (const int*)d_in[5];
  float* out = (float*)d_out;
  u32* ws = (u32*)d_ws;  // needs ~8.5 MB

  hipLaunchKernelGGL(prep_kernel, dim3(261), dim3(256), 0, stream,
                     in_pc, weights, weight_res, ws);
  // 1024 blocks x 4 waves x 4 points = 16384 points
  hipLaunchKernelGGL(pconv_main, dim3(1024), dim3(256), 0, stream,
                     ws, bias, w_weights, neighbor_id, out);
}

// Round 7
// 104.210 us; speedup vs baseline: 1.0353x; 1.0353x over previous
//
#include <hip/hip_runtime.h>

#define PP 16384
#define SQH 0.70710678118654752440f  // sqrt(0.5)

typedef unsigned int u32;
typedef unsigned short u16;
typedef __attribute__((ext_vector_type(8))) short bfrag;    // 8 bf16
typedef __attribute__((ext_vector_type(4))) float ffrag;    // 16x16 C/D
typedef __attribute__((ext_vector_type(16))) float ffrag16; // 32x32 C/D
typedef __attribute__((ext_vector_type(4))) float f4;

union BU { bfrag v; uint4 u; };

// proven bf16 pair pack (round-half-up).
// r1: inline-asm v_cvt_pk_bf16_f32 broke correctness (absmax 40).
// r2: 4-pt "spill" was nid[4][16] scratch (rule #20), not a-regs.
// r3: gather issue-count reduction NEUTRAL (latency-bound).
// r4: 1-pt occupancy test CONFOUNDED by nid[16] scratch (64 B/thread).
// r5: scratch-free nid on 2-pt NEUTRAL -> pconv ~27us, fixed ~76us.
// r6: clean 4-pt pipeline slightly NEGATIVE (serial 2-pass per wave).
// r7: clean 1-pt (r4 body + int4 nid): the un-confounded occupancy A/B.
__device__ __forceinline__ u32 pk2(float a, float b) {
  u32 ua = __float_as_uint(a), ub = __float_as_uint(b);
  return ((ua + 0x8000u) >> 16) | ((ub + 0x8000u) & 0xffff0000u);
}

// ---- workspace layout (bytes) ----
// [0, XTB_B)        xTb: (P+1, 8, 16) bf16 old layout (su residual reads)
// [XTB_B, +18432)   WB : phase-2 conv-weight B-frags [2][9][64] uint4
// [+18432, +2048)   WR : residual B-frags [2][64] uint4
// [XG_B, +XTB_B)    xG : gather-permuted copy, pos = col*4 + t
#define XTB_B ((size_t)(PP + 1) * 256)
#define WB_B  XTB_B
#define WR_B  (XTB_B + 18432)
#define XG_B  (WR_B + 2048)
#define XG_W  (XG_B / 4)

// Blocks 0..255: LDS-transpose 64 points each; writes BOTH xTb layouts.
// Blocks 256..260: WB/WR frag packing; block 256 also zeroes the pad rows.
__global__ __launch_bounds__(256) void prep_kernel(
    const float* __restrict__ in_pc, const float* __restrict__ weights,
    const float* __restrict__ weight_res, u32* __restrict__ ws) {
  __shared__ u32 T[64 * 72];  // 64 points x 64 dwords, stride 72 (bank rotation)
  const int blk = blockIdx.x, t = threadIdx.x;
  if (blk < 256) {
    const int p0 = blk * 64;
    const int pl = t >> 2, i4 = t & 3;
#pragma unroll
    for (int b = 0; b < 8; ++b) {  // coalesced: consecutive t -> consecutive 16B
      f4 v = *(const f4*)(in_pc + ((size_t)b * PP + p0 + pl) * 16 + i4 * 4);
      T[pl * 72 + b * 8 + i4 * 2]     = pk2(v.x, v.y);
      T[pl * 72 + b * 8 + i4 * 2 + 1] = pk2(v.z, v.w);
    }
    __syncthreads();
#pragma unroll
    for (int k = 0; k < 4; ++k) {  // old layout: coalesced uint4 copies
      int idx = k * 256 + t;
      int pl2 = idx >> 4, c2 = (idx & 15) * 4;
      uint4 v = *(const uint4*)&T[pl2 * 72 + c2];
      *(uint4*)&ws[(size_t)(p0 + pl2) * 64 + c2] = v;
    }
    // gather layout xG: new dword nd_ (col=nd_>>1, t0=2*(nd_&1)) =
    //   old_u16[t0*32+col] | old_u16[(t0+1)*32+col] << 16
#pragma unroll
    for (int k = 0; k < 4; ++k) {
      int idx = k * 256 + t;
      int pl2 = idx >> 4, m = idx & 15;
      u32 T0 = T[pl2 * 72 + m];
      u32 T1 = T[pl2 * 72 + 16 + m];
      u32 T2 = T[pl2 * 72 + 32 + m];
      u32 T3 = T[pl2 * 72 + 48 + m];
      uint4 w;
      w.x = (T0 & 0xffffu) | (T1 << 16);         // col=2m,   t=0|1
      w.y = (T2 & 0xffffu) | (T3 << 16);         // col=2m,   t=2|3
      w.z = (T0 >> 16)     | (T1 & 0xffff0000u); // col=2m+1, t=0|1
      w.w = (T2 >> 16)     | (T3 & 0xffff0000u); // col=2m+1, t=2|3
      *(uint4*)&ws[XG_W + (size_t)(p0 + pl2) * 64 + m * 4] = w;
    }
    return;
  }
  if (blk == 256 && t < 32) {  // zero pad row PP in both layouts
    *(uint2*)&ws[(size_t)PP * 64 + t * 2] = make_uint2(0u, 0u);
    *(uint2*)&ws[XG_W + (size_t)PP * 64 + t * 2] = make_uint2(0u, 0u);
  }
  int e = (blk - 256) * 256 + t;
  if (e < 1152) {  // WB frag (nt, ks, l): B[k=ks*32+(l>>4)*8+j][n=nt*16+(l&15)]
    int nt = e / 576, rem = e - nt * 576;
    int ks = rem >> 6, l = rem & 63;
    int quad = l >> 4, n = l & 15;
    int k0 = ks * 32 + quad * 8;
    uint4 pkd = make_uint4(0u, 0u, 0u, 0u);
    if (k0 < 272) {
      int w = k0 >> 4, i0 = k0 & 15;
      const float* src = weights + w * 512 + (nt * 16 + n) * 16 + i0;
      f4 lo = *(const f4*)src;
      f4 hi = *(const f4*)(src + 4);
      pkd = make_uint4(pk2(lo.x, lo.y), pk2(lo.z, lo.w), pk2(hi.x, hi.y), pk2(hi.z, hi.w));
    }
    *(uint4*)((char*)ws + WB_B + (size_t)e * 16) = pkd;
  } else if (e < 1280) {  // WR frag
    int l2 = e - 1152, nt = l2 >> 6, l = l2 & 63;
    int quad = l >> 4, n = l & 15;
    uint4 pkd = make_uint4(0u, 0u, 0u, 0u);
    if (quad < 2) {
      const float* src = weight_res + (nt * 16 + n) * 16 + quad * 8;
      f4 lo = *(const f4*)src;
      f4 hi = *(const f4*)(src + 4);
      pkd = make_uint4(pk2(lo.x, lo.y), pk2(lo.z, lo.w), pk2(hi.x, hi.y), pk2(hi.z, hi.w));
    }
    *(uint4*)((char*)ws + WR_B + (size_t)(e - 1152) * 16) = pkd;
  }
}

// gather one point's 16 neighbor rows into packed A dwords.
// Neighbor ids arrive as two int4 (this half-wave's 8 rows) — component
// access only, so everything stays in VGPRs (no rule-#20 scratch array).
__device__ __forceinline__ void gather_pt(u32 (&ad)[4][4], int4 na, int4 nb,
                                          const u16* __restrict__ xG, int col) {
#define GJ(j, r0, r1)                                                        \
  {                                                                          \
    uint2 d = *(const uint2*)(xG + (size_t)(u32)(r0) * 128 + col * 4);       \
    uint2 e = *(const uint2*)(xG + (size_t)(u32)(r1) * 128 + col * 4);       \
    ad[0][j] = (d.x & 0xffffu) | (e.x << 16);                                \
    ad[1][j] = (d.x >> 16)     | (e.x & 0xffff0000u);                        \
    ad[2][j] = (d.y & 0xffffu) | (e.y << 16);                                \
    ad[3][j] = (d.y >> 16)     | (e.y & 0xffff0000u);                        \
  }
  GJ(0, na.x, na.y)
  GJ(1, na.z, na.w)
  GJ(2, nb.x, nb.y)
  GJ(3, nb.z, nb.w)
#undef GJ
}

// Main: 4096 blocks x 4 waves; ONE point per wave, NO scratch (int4 nid).
// LDS 18944 B -> 8 blocks/CU; launch_bounds(256,6) caps VGPR at 84 (clean
// register inventory ~70) -> 6-8 waves/SIMD vs the 2-pt kernel's 4: the
// un-confounded occupancy experiment (r4's was polluted by nid scratch).
// Phase-2 rows 8..15 duplicate 0..7 via broadcast LDS reads (free) and are
// discarded. Zero barriers.
__global__ __launch_bounds__(256, 6) void pconv_main(
    const u32* __restrict__ ws,
    const float* __restrict__ bias,      // (P, 32) f32
    const float* __restrict__ wwg,       // (P, 16, 17) f32
    const int*  __restrict__ nidg,       // (P, 16) i32
    float* __restrict__ out)             // (8, P, 32) f32
{
  __shared__ __attribute__((aligned(16))) u16 Abuf[4 * 8 * 296];  // 18944 B

  const u16*  __restrict__ xTb = (const u16*)ws;
  const u16*  __restrict__ xG  = (const u16*)((const char*)ws + XG_B);
  const uint4* __restrict__ WB = (const uint4*)((const char*)ws + WB_B);
  const uint4* __restrict__ WR = (const uint4*)((const char*)ws + WR_B);

  const int tid = threadIdx.x;
  const int wid = __builtin_amdgcn_readfirstlane(tid >> 6);
  const int lane = tid & 63;
  const int lo16 = lane & 15, quad = lane >> 4;   // 16x16 MFMA role
  const int col = lane & 31, h = lane >> 5;       // 32x32 MFMA role
  u16* __restrict__ Aw = Abuf + wid * (8 * 296);

  const int p = blockIdx.x * 4 + wid;             // one point per wave

  // zero K-tail [272,288) of the 8 A2 rows (lanes 0..31)
  if (lane < 32) {
    int r = lane >> 2, c = lane & 3;
    *(uint2*)(Aw + r * 296 + 272 + c * 4) = make_uint2(0u, 0u);
  }

  // ---- issue all independent loads up front ----
  // this half-wave's 8 neighbor ids: two int4 loads, stay in VGPRs
  const int* nr = nidg + (size_t)p * 16 + h * 8;
  int4 na = *(const int4*)nr;
  int4 nb = *(const int4*)(nr + 4);

  BU bb;  // phase-1 ww B-frag packed in-kernel
  {
    float v[8];
#pragma unroll
    for (int idx = 0; idx < 8; ++idx) {
      float x = 0.f;
      if (col < 17)
        x = wwg[(size_t)p * 272 + (h * 8 + idx) * 17 + col];
      v[idx] = x;
    }
    bb.u = make_uint4(pk2(v[0], v[1]), pk2(v[2], v[3]),
                      pk2(v[4], v[5]), pk2(v[6], v[7]));
  }

  u32 a[4][4];  // packed A dwords, 16 VGPRs
  gather_pt(a, na, nb, xG, col);

  // bias + residual self row + residual B-frags
  float blo = bias[(size_t)p * 32 + lo16];
  float bhi = bias[(size_t)p * 32 + 16 + lo16];
  BU su;
  su.u = make_uint4(0u, 0u, 0u, 0u);
  if (quad < 2)  // row lo16 duplicates b = lo16&7 (rows 8..15 discarded)
    su.u = *(const uint4*)(xTb + (size_t)p * 128 + (lo16 & 7) * 16 + quad * 8);
  BU rb0, rb1;
  rb0.u = WR[lane];
  rb1.u = WR[64 + lane];

  // ---- phase 1: one point -> A2 rows 0..7 in LDS ----
#pragma unroll
  for (int t = 0; t < 4; ++t) {
    BU aa;
    aa.u = make_uint4(a[t][0], a[t][1], a[t][2], a[t][3]);
    ffrag16 c = {};
    c = __builtin_amdgcn_mfma_f32_32x32x16_bf16(aa.v, bb.v, c, 0, 0, 0);
    if (col < 17) {
#pragma unroll
      for (int q = 0; q < 4; ++q) {
        int r = 2 * t + (q >> 1);            // 0..7
        int i0 = 4 * h + 8 * (q & 1);
        u16* dst = Aw + r * 296 + col * 16 + i0;
        *(uint2*)dst = make_uint2(pk2(c[4 * q + 0], c[4 * q + 1]),
                                  pk2(c[4 * q + 2], c[4 * q + 3]));
      }
    }
  }

  // ---- phase 2: C[8x32] = A2[8x288] * W (M=16 shape, rows 8..15 dup) ----
  const int arow = lo16 & 7;  // 2-way same-address LDS read = free broadcast
  ffrag acc0 = {0.f, 0.f, 0.f, 0.f}, acc1 = {0.f, 0.f, 0.f, 0.f};
#pragma unroll
  for (int ks = 0; ks < 9; ++ks) {
    bfrag af = *(const bfrag*)(Aw + arow * 296 + ks * 32 + quad * 8);
    BU b0, b1;
    b0.u = WB[ks * 64 + lane];
    b1.u = WB[576 + ks * 64 + lane];
    acc0 = __builtin_amdgcn_mfma_f32_16x16x32_bf16(af, b0.v, acc0, 0, 0, 0);
    acc1 = __builtin_amdgcn_mfma_f32_16x16x32_bf16(af, b1.v, acc1, 0, 0, 0);
  }
  ffrag rz = {0.f, 0.f, 0.f, 0.f};
  ffrag res0 = __builtin_amdgcn_mfma_f32_16x16x32_bf16(su.v, rb0.v, rz, 0, 0, 0);
  ffrag res1 = __builtin_amdgcn_mfma_f32_16x16x32_bf16(su.v, rb1.v, rz, 0, 0, 0);

  // ---- epilogue: bias/ELU/mix -> LDS f32 [8][40] -> full-line stores ----
  float* Ef = (float*)Aw;
  if (quad < 2) {  // rows r = quad*4+j in 0..7 are the valid ones
#pragma unroll
    for (int j = 0; j < 4; ++j) {
      int r = quad * 4 + j;
      float c0 = acc0[j] + blo;
      float c1 = acc1[j] + bhi;
      float e0 = c0 > 0.f ? c0 : (__expf(c0) - 1.f);
      float e1 = c1 > 0.f ? c1 : (__expf(c1) - 1.f);
      Ef[r * 40 + lo16]      = SQH * e0 + SQH * res0[j];
      Ef[r * 40 + 16 + lo16] = SQH * e1 + SQH * res1[j];
    }
  }
  {
    int rr = lane >> 3, cc = lane & 7;   // 8 rows x 8 f4-cols = 64 lanes
    f4 v = *(const f4*)(Ef + rr * 40 + cc * 4);
    *(f4*)(out + ((size_t)rr * PP + p) * 32 + cc * 4) = v;
  }
}

extern "C" void kernel_launch(void* const* d_in, const int* in_sizes, int n_in,
                              void* d_out, int out_size, void* d_ws, size_t ws_size,
                              hipStream_t stream) {
  const float* in_pc       = (const float*)d_in[0];
  const float* weights     = (const float*)d_in[1];
  const float* bias        = (const float*)d_in[2];
  const float* w_weights   = (const float*)d_in[3];
  const float* weight_res  = (const float*)d_in[4];
  const int*   neighbor_id = (const int*)d_in[5];
  float* out = (float*)d_out;
  u32* ws = (u32*)d_ws;  // needs ~8.5 MB

  hipLaunchKernelGGL(prep_kernel, dim3(261), dim3(256), 0, stream,
                     in_pc, weights, weight_res, ws);
  // 4096 blocks x 4 waves x 1 point = 16384 points
  hipLaunchKernelGGL(pconv_main, dim3(4096), dim3(256), 0, stream,
                     ws, bias, w_weights, neighbor_id, out);
}

// Round 8
// 103.332 us; speedup vs baseline: 1.0441x; 1.0085x over previous
//
#include <hip/hip_runtime.h>

#define PP 16384
#define SQH 0.70710678118654752440f  // sqrt(0.5)

typedef unsigned int u32;
typedef unsigned short u16;
typedef __attribute__((ext_vector_type(8))) short bfrag;    // 8 bf16
typedef __attribute__((ext_vector_type(4))) float ffrag;    // 16x16 C/D
typedef __attribute__((ext_vector_type(16))) float ffrag16; // 32x32 C/D
typedef __attribute__((ext_vector_type(4))) float f4;

union BU { bfrag v; uint4 u; };

// proven bf16 pair pack (round-half-up).
// Session ledger:
// r1: inline-asm v_cvt_pk_bf16_f32 broke correctness (absmax 40).
// r2: 4-pt "spill" was nid[4][16] scratch (rule #20), not a-regs.
// r3: gather issue-count reduction (xG dwordx2) NEUTRAL (latency-bound).
// r4: 1-pt occupancy test CONFOUNDED by nid[16] scratch (64 B/thread).
// r5: scratch-free nid on 2-pt NEUTRAL -> pconv ~27us, fixed ~76us.
// r6: clean 4-pt pipeline slightly NEGATIVE (serial 2-pass per wave).
// r7: clean 1-pt / 2x occupancy NEUTRAL -> TLP not the limiter.
// r8: revert to best clean variant (r5). Plateau 102.6-104.5 across all
//     structural levers; fixed harness cost (~76us incl. 45us ws-fill at
//     75% HBM peak) dominates the measurement.
__device__ __forceinline__ u32 pk2(float a, float b) {
  u32 ua = __float_as_uint(a), ub = __float_as_uint(b);
  return ((ua + 0x8000u) >> 16) | ((ub + 0x8000u) & 0xffff0000u);
}

// ---- workspace layout (bytes) ----
// [0, XTB_B)        xTb: (P+1, 8, 16) bf16 old layout (su residual reads)
// [XTB_B, +18432)   WB : phase-2 conv-weight B-frags [2][9][64] uint4
// [+18432, +2048)   WR : residual B-frags [2][64] uint4
// [XG_B, +XTB_B)    xG : gather-permuted copy, pos = col*4 + t
#define XTB_B ((size_t)(PP + 1) * 256)
#define WB_B  XTB_B
#define WR_B  (XTB_B + 18432)
#define XG_B  (WR_B + 2048)
#define XG_W  (XG_B / 4)

// Blocks 0..255: LDS-transpose 64 points each; writes BOTH xTb layouts.
// Blocks 256..260: WB/WR frag packing; block 256 also zeroes the pad rows.
__global__ __launch_bounds__(256) void prep_kernel(
    const float* __restrict__ in_pc, const float* __restrict__ weights,
    const float* __restrict__ weight_res, u32* __restrict__ ws) {
  __shared__ u32 T[64 * 72];  // 64 points x 64 dwords, stride 72 (bank rotation)
  const int blk = blockIdx.x, t = threadIdx.x;
  if (blk < 256) {
    const int p0 = blk * 64;
    const int pl = t >> 2, i4 = t & 3;
#pragma unroll
    for (int b = 0; b < 8; ++b) {  // coalesced: consecutive t -> consecutive 16B
      f4 v = *(const f4*)(in_pc + ((size_t)b * PP + p0 + pl) * 16 + i4 * 4);
      T[pl * 72 + b * 8 + i4 * 2]     = pk2(v.x, v.y);
      T[pl * 72 + b * 8 + i4 * 2 + 1] = pk2(v.z, v.w);
    }
    __syncthreads();
#pragma unroll
    for (int k = 0; k < 4; ++k) {  // old layout: coalesced uint4 copies
      int idx = k * 256 + t;
      int pl2 = idx >> 4, c2 = (idx & 15) * 4;
      uint4 v = *(const uint4*)&T[pl2 * 72 + c2];
      *(uint4*)&ws[(size_t)(p0 + pl2) * 64 + c2] = v;
    }
    // gather layout xG: new dword nd_ (col=nd_>>1, t0=2*(nd_&1)) =
    //   old_u16[t0*32+col] | old_u16[(t0+1)*32+col] << 16
#pragma unroll
    for (int k = 0; k < 4; ++k) {
      int idx = k * 256 + t;
      int pl2 = idx >> 4, m = idx & 15;
      u32 T0 = T[pl2 * 72 + m];
      u32 T1 = T[pl2 * 72 + 16 + m];
      u32 T2 = T[pl2 * 72 + 32 + m];
      u32 T3 = T[pl2 * 72 + 48 + m];
      uint4 w;
      w.x = (T0 & 0xffffu) | (T1 << 16);         // col=2m,   t=0|1
      w.y = (T2 & 0xffffu) | (T3 << 16);         // col=2m,   t=2|3
      w.z = (T0 >> 16)     | (T1 & 0xffff0000u); // col=2m+1, t=0|1
      w.w = (T2 >> 16)     | (T3 & 0xffff0000u); // col=2m+1, t=2|3
      *(uint4*)&ws[XG_W + (size_t)(p0 + pl2) * 64 + m * 4] = w;
    }
    return;
  }
  if (blk == 256 && t < 32) {  // zero pad row PP in both layouts
    *(uint2*)&ws[(size_t)PP * 64 + t * 2] = make_uint2(0u, 0u);
    *(uint2*)&ws[XG_W + (size_t)PP * 64 + t * 2] = make_uint2(0u, 0u);
  }
  int e = (blk - 256) * 256 + t;
  if (e < 1152) {  // WB frag (nt, ks, l): B[k=ks*32+(l>>4)*8+j][n=nt*16+(l&15)]
    int nt = e / 576, rem = e - nt * 576;
    int ks = rem >> 6, l = rem & 63;
    int quad = l >> 4, n = l & 15;
    int k0 = ks * 32 + quad * 8;
    uint4 pkd = make_uint4(0u, 0u, 0u, 0u);
    if (k0 < 272) {
      int w = k0 >> 4, i0 = k0 & 15;
      const float* src = weights + w * 512 + (nt * 16 + n) * 16 + i0;
      f4 lo = *(const f4*)src;
      f4 hi = *(const f4*)(src + 4);
      pkd = make_uint4(pk2(lo.x, lo.y), pk2(lo.z, lo.w), pk2(hi.x, hi.y), pk2(hi.z, hi.w));
    }
    *(uint4*)((char*)ws + WB_B + (size_t)e * 16) = pkd;
  } else if (e < 1280) {  // WR frag
    int l2 = e - 1152, nt = l2 >> 6, l = l2 & 63;
    int quad = l >> 4, n = l & 15;
    uint4 pkd = make_uint4(0u, 0u, 0u, 0u);
    if (quad < 2) {
      const float* src = weight_res + (nt * 16 + n) * 16 + quad * 8;
      f4 lo = *(const f4*)src;
      f4 hi = *(const f4*)(src + 4);
      pkd = make_uint4(pk2(lo.x, lo.y), pk2(lo.z, lo.w), pk2(hi.x, hi.y), pk2(hi.z, hi.w));
    }
    *(uint4*)((char*)ws + WR_B + (size_t)(e - 1152) * 16) = pkd;
  }
}

// gather one point's 16 neighbor rows into packed A dwords.
// Neighbor ids arrive as two int4 (this half-wave's 8 rows) — component
// access only, so everything stays in VGPRs (no rule-#20 scratch array).
__device__ __forceinline__ void gather_pt(u32 (&ad)[4][4], int4 na, int4 nb,
                                          const u16* __restrict__ xG, int col) {
#define GJ(j, r0, r1)                                                        \
  {                                                                          \
    uint2 d = *(const uint2*)(xG + (size_t)(u32)(r0) * 128 + col * 4);       \
    uint2 e = *(const uint2*)(xG + (size_t)(u32)(r1) * 128 + col * 4);       \
    ad[0][j] = (d.x & 0xffffu) | (e.x << 16);                                \
    ad[1][j] = (d.x >> 16)     | (e.x & 0xffff0000u);                        \
    ad[2][j] = (d.y & 0xffffu) | (e.y << 16);                                \
    ad[3][j] = (d.y >> 16)     | (e.y & 0xffff0000u);                        \
  }
  GJ(0, na.x, na.y)
  GJ(1, na.z, na.w)
  GJ(2, nb.x, nb.y)
  GJ(3, nb.z, nb.w)
#undef GJ
}

// Main: 2048 blocks x 4 waves; ONE point-pair per wave (proven register
// footprint). ww B-frags packed in-kernel. nid in VGPRs (int4), no scratch.
// Zero barriers.
__global__ __launch_bounds__(256, 4) void pconv_main(
    const u32* __restrict__ ws,
    const float* __restrict__ bias,      // (P, 32) f32
    const float* __restrict__ wwg,       // (P, 16, 17) f32
    const int*  __restrict__ nidg,       // (P, 16) i32
    float* __restrict__ out)             // (8, P, 32) f32
{
  __shared__ __attribute__((aligned(16))) u16 Abuf[4 * 16 * 296];  // 37888 B

  const u16*  __restrict__ xTb = (const u16*)ws;
  const u16*  __restrict__ xG  = (const u16*)((const char*)ws + XG_B);
  const uint4* __restrict__ WB = (const uint4*)((const char*)ws + WB_B);
  const uint4* __restrict__ WR = (const uint4*)((const char*)ws + WR_B);

  const int tid = threadIdx.x;
  const int wid = __builtin_amdgcn_readfirstlane(tid >> 6);
  const int lane = tid & 63;
  const int lo16 = lane & 15, quad = lane >> 4;   // 16x16 MFMA role
  const int col = lane & 31, h = lane >> 5;       // 32x32 MFMA role
  u16* __restrict__ Aw = Abuf + wid * (16 * 296);

  const int p0 = (blockIdx.x * 4 + wid) * 2;

  // zero K-tail [272,288) of all 16 A2 rows
  {
    int r = lane >> 2, c = lane & 3;
    *(uint2*)(Aw + r * 296 + 272 + c * 4) = make_uint2(0u, 0u);
  }

  // ---- issue all independent loads up front ----
  // this half-wave's 8 neighbor ids per point: two int4 loads, stay in VGPRs
  const int* nrow0 = nidg + (size_t)p0 * 16 + h * 8;
  const int* nrow1 = nidg + (size_t)(p0 + 1) * 16 + h * 8;
  int4 n0a = *(const int4*)nrow0;
  int4 n0b = *(const int4*)(nrow0 + 4);
  int4 n1a = *(const int4*)nrow1;
  int4 n1b = *(const int4*)(nrow1 + 4);

  BU bb0, bb1;  // phase-1 ww B-frags packed in-kernel
  {
    float v0[8], v1[8];
#pragma unroll
    for (int idx = 0; idx < 8; ++idx) {
      float x0 = 0.f, x1 = 0.f;
      if (col < 17) {
        x0 = wwg[(size_t)p0 * 272 + (h * 8 + idx) * 17 + col];
        x1 = wwg[(size_t)(p0 + 1) * 272 + (h * 8 + idx) * 17 + col];
      }
      v0[idx] = x0; v1[idx] = x1;
    }
    bb0.u = make_uint4(pk2(v0[0], v0[1]), pk2(v0[2], v0[3]), pk2(v0[4], v0[5]), pk2(v0[6], v0[7]));
    bb1.u = make_uint4(pk2(v1[0], v1[1]), pk2(v1[2], v1[3]), pk2(v1[4], v1[5]), pk2(v1[6], v1[7]));
  }

  u32 a0[4][4], a1[4][4];  // packed A dwords, 32 VGPRs total
  gather_pt(a0, n0a, n0b, xG, col);
  gather_pt(a1, n1a, n1b, xG, col);

  // hoist bias + residual self rows + residual B-frags (off the tail)
  float blo[4], bhi[4];
#pragma unroll
  for (int j = 0; j < 4; ++j) {
    int p_e = p0 + ((quad * 4 + j) >> 3);
    blo[j] = bias[(size_t)p_e * 32 + lo16];
    bhi[j] = bias[(size_t)p_e * 32 + 16 + lo16];
  }
  BU su;
  su.u = make_uint4(0u, 0u, 0u, 0u);
  {
    const int p_r = p0 + (lo16 >> 3), b_r = lo16 & 7;
    if (quad < 2)
      su.u = *(const uint4*)(xTb + (size_t)p_r * 128 + b_r * 16 + quad * 8);
  }
  BU rb0, rb1;
  rb0.u = WR[lane];
  rb1.u = WR[64 + lane];

  // ---- phase 1: two points -> A2 in LDS ----
#pragma unroll
  for (int pt = 0; pt < 2; ++pt) {
    const u32 (&ad)[4][4] = pt ? a1 : a0;
    BU bb = pt ? bb1 : bb0;
#pragma unroll
    for (int t = 0; t < 4; ++t) {
      BU aa;
      aa.u = make_uint4(ad[t][0], ad[t][1], ad[t][2], ad[t][3]);
      ffrag16 c = {};
      c = __builtin_amdgcn_mfma_f32_32x32x16_bf16(aa.v, bb.v, c, 0, 0, 0);
      if (col < 17) {
#pragma unroll
        for (int q = 0; q < 4; ++q) {
          int r = pt * 8 + 2 * t + (q >> 1);
          int i0 = 4 * h + 8 * (q & 1);
          u16* dst = Aw + r * 296 + col * 16 + i0;
          *(uint2*)dst = make_uint2(pk2(c[4 * q + 0], c[4 * q + 1]),
                                    pk2(c[4 * q + 2], c[4 * q + 3]));
        }
      }
    }
  }

  // ---- phase 2: C[16x32] = A2[16x288] * W ----
  ffrag acc0 = {0.f, 0.f, 0.f, 0.f}, acc1 = {0.f, 0.f, 0.f, 0.f};
#pragma unroll
  for (int ks = 0; ks < 9; ++ks) {
    bfrag af = *(const bfrag*)(Aw + lo16 * 296 + ks * 32 + quad * 8);
    BU b0, b1;
    b0.u = WB[ks * 64 + lane];
    b1.u = WB[576 + ks * 64 + lane];
    acc0 = __builtin_amdgcn_mfma_f32_16x16x32_bf16(af, b0.v, acc0, 0, 0, 0);
    acc1 = __builtin_amdgcn_mfma_f32_16x16x32_bf16(af, b1.v, acc1, 0, 0, 0);
  }
  ffrag rz = {0.f, 0.f, 0.f, 0.f};
  ffrag res0 = __builtin_amdgcn_mfma_f32_16x16x32_bf16(su.v, rb0.v, rz, 0, 0, 0);
  ffrag res1 = __builtin_amdgcn_mfma_f32_16x16x32_bf16(su.v, rb1.v, rz, 0, 0, 0);

  // ---- epilogue: bias/ELU/mix -> LDS f32 [16][40] -> full-line stores ----
  float* Ef = (float*)Aw;
#pragma unroll
  for (int j = 0; j < 4; ++j) {
    int r = quad * 4 + j;
    float c0 = acc0[j] + blo[j];
    float c1 = acc1[j] + bhi[j];
    float e0 = c0 > 0.f ? c0 : (__expf(c0) - 1.f);
    float e1 = c1 > 0.f ? c1 : (__expf(c1) - 1.f);
    Ef[r * 40 + lo16]      = SQH * e0 + SQH * res0[j];
    Ef[r * 40 + 16 + lo16] = SQH * e1 + SQH * res1[j];
  }
#pragma unroll
  for (int k = 0; k < 2; ++k) {
    int rr = (lane >> 3) + 8 * k;
    int cc = lane & 7;
    f4 v = *(const f4*)(Ef + rr * 40 + cc * 4);
    int p_s = p0 + (rr >> 3), b_s = rr & 7;
    *(f4*)(out + ((size_t)b_s * PP + p_s) * 32 + cc * 4) = v;
  }
}

extern "C" void kernel_launch(void* const* d_in, const int* in_sizes, int n_in,
                              void* d_out, int out_size, void* d_ws, size_t ws_size,
                              hipStream_t stream) {
  const float* in_pc       = (const float*)d_in[0];
  const float* weights     = (const float*)d_in[1];
  const float* bias        = (const float*)d_in[2];
  const float* w_weights   = (const float*)d_in[3];
  const float* weight_res  = (const float*)d_in[4];
  const int*   neighbor_id = (const int*)d_in[5];
  float* out = (float*)d_out;
  u32* ws = (u32*)d_ws;  // needs ~8.5 MB

  hipLaunchKernelGGL(prep_kernel, dim3(261), dim3(256), 0, stream,
                     in_pc, weights, weight_res, ws);
  // 2048 blocks x 4 waves x 2 points = 16384 points
  hipLaunchKernelGGL(pconv_main, dim3(2048), dim3(256), 0, stream,
                     ws, bias, w_weights, neighbor_id, out);
}